// Round 13
// baseline (376.155 us; speedup 1.0000x reference)
//
#include <hip/hip_runtime.h>
#include <hip/hip_fp16.h>
#include <math.h>

// Problem constants: N=50000, E=1600000, F=64, H=128, ED=2, A=16
// NOTE: src-index packing below requires n < 65536 (n=50000 here).
#define H_DIM 128
#define BWID 64       // dsts per bucket (bucket = dst >> 6) — 782 buckets
#define BMAX 1024     // max buckets (n <= 65536)
#define CHUNK 2048    // edges per block in count/bin — 782 edge blocks

// ---------------------------------------------------------------------------
// K0a: fused {prep | count}. Last block does the tiny precomputes:
//   c[0..3] = We^T @ a_edge; vs1/vd1 = W1 @ a_s/a_d; vs2/vd2 = W2 @ a_s/a_d.
// All other blocks do the bucket histogram (LDS pre-aggregated).
__global__ __launch_bounds__(256) void prep_count_kernel(
        const float* __restrict__ We1, const float* __restrict__ ae1,
        const float* __restrict__ We2, const float* __restrict__ ae2,
        const float* __restrict__ W1, const float* __restrict__ as1,
        const float* __restrict__ ad1,
        const float* __restrict__ W2, const float* __restrict__ as2,
        const float* __restrict__ ad2,
        float* __restrict__ c, float* __restrict__ vs1,
        float* __restrict__ vd1, float* __restrict__ vs2,
        float* __restrict__ vd2,
        const int* __restrict__ ei, int* __restrict__ gcnt,
        int E, int B, int ebg) {
    int t = threadIdx.x;
    if ((int)blockIdx.x == ebg) {
        if (t < 64) {
            float s = 0.f, d = 0.f;
            for (int h = 0; h < 128; ++h) {
                float w = W1[t * 128 + h];
                s += w * as1[h];
                d += w * ad1[h];
            }
            vs1[t] = s; vd1[t] = d;
        } else if (t < 192) {
            int k = t - 64;
            float s = 0.f, d = 0.f;
            for (int h = 0; h < 128; ++h) {
                float w = W2[k * 128 + h];
                s += w * as2[h];
                d += w * ad2[h];
            }
            vs2[k] = s; vd2[k] = d;
        } else {
            int l = t - 192;  // lane of wave 3
            float a1x = ae1[l], a1y = ae1[l + 64];
            float a2x = ae2[l], a2y = ae2[l + 64];
            float v0 = We1[l] * a1x + We1[l + 64] * a1y;
            float v1 = We1[128 + l] * a1x + We1[192 + l] * a1y;
            float v2 = We2[l] * a2x + We2[l + 64] * a2y;
            float v3 = We2[128 + l] * a2x + We2[192 + l] * a2y;
            for (int off = 32; off; off >>= 1) {
                v0 += __shfl_xor(v0, off);
                v1 += __shfl_xor(v1, off);
                v2 += __shfl_xor(v2, off);
                v3 += __shfl_xor(v3, off);
            }
            if (l == 0) { c[0] = v0; c[1] = v1; c[2] = v2; c[3] = v3; }
        }
        return;
    }
    __shared__ int hist[BMAX];
    for (int i = t; i < B; i += 256) hist[i] = 0;
    __syncthreads();
    int lo = blockIdx.x * CHUNK, hi = min(lo + CHUNK, E);
    for (int e = lo + t; e < hi; e += 256)
        atomicAdd(&hist[ei[E + e] >> 6], 1);
    __syncthreads();
    for (int i = t; i < B; i += 256)
        if (hist[i]) atomicAdd(&gcnt[i], hist[i]);
}

// ---------------------------------------------------------------------------
// K2: scan bucket counts -> bstart (excl prefix), seed gcur, write tails
__global__ void bscan_kernel(const int* __restrict__ gcnt, int* __restrict__ bstart,
                             int* __restrict__ gcur, int* __restrict__ rowptr,
                             int B, int n, int E) {
    __shared__ int s[BMAX];
    int t = threadIdx.x;  // BMAX (1024) threads
    int v0 = (t < B) ? gcnt[t] : 0;
    s[t] = v0;
    __syncthreads();
    for (int off = 1; off < BMAX; off <<= 1) {
        int v = (t >= off) ? s[t - off] : 0;
        __syncthreads();
        s[t] += v;
        __syncthreads();
    }
    if (t < B) {
        int excl = s[t] - v0;
        bstart[t] = excl;
        gcur[t] = excl;
    }
    if (t == 0) { bstart[B] = E; rowptr[n] = E; }
}

// ---------------------------------------------------------------------------
// K3: fused {bin | hshd64}. Blocks [0, ebg) bin edges by bucket;
// blocks [ebg, ebg+wgrid) compute hs/hd + x->fp16 conversion.
__global__ __launch_bounds__(256) void bin_hshd_kernel(
        const int* __restrict__ ei, const float* __restrict__ ea,
        const float* __restrict__ cvec, int* __restrict__ gcur,
        int2* __restrict__ binned, int E, int B, int ebg,
        const float* __restrict__ x, const float* __restrict__ vs,
        const float* __restrict__ vd, float* __restrict__ hs,
        float* __restrict__ hd, __half* __restrict__ xh, int n) {
    int tid = threadIdx.x;
    if ((int)blockIdx.x >= ebg) {
        int w = (((int)blockIdx.x - ebg) * 256 + tid) >> 6;
        int lane = tid & 63;
        if (w >= n) return;
        float xv = x[(size_t)w * 64 + lane];
        xh[(size_t)w * 64 + lane] = __float2half(xv);
        float ss = xv * vs[lane];
        float sd = xv * vd[lane];
        for (int off = 32; off; off >>= 1) {
            ss += __shfl_xor(ss, off);
            sd += __shfl_xor(sd, off);
        }
        if (lane == 0) { hs[w] = ss; hd[w] = sd; }
        return;
    }
    __shared__ int cnt[BMAX];
    __shared__ int base[BMAX];
    for (int i = tid; i < B; i += 256) cnt[i] = 0;
    __syncthreads();
    int lo = blockIdx.x * CHUNK, hi = min(lo + CHUNK, E);
    for (int e = lo + tid; e < hi; e += 256)
        atomicAdd(&cnt[ei[E + e] >> 6], 1);
    __syncthreads();
    for (int i = tid; i < B; i += 256) {
        int c = cnt[i];
        base[i] = c ? atomicAdd(&gcur[i], c) : 0;
        cnt[i] = 0;  // reuse as local cursor
    }
    __syncthreads();
    float c0 = cvec[0], c1 = cvec[1], c2 = cvec[2], c3 = cvec[3];
    for (int e = lo + tid; e < hi; e += 256) {
        int s = ei[e], d = ei[E + e];
        float2 v = ((const float2*)ea)[e];
        float d1 = c0 * v.x + c1 * v.y;
        float d2 = c2 * v.x + c3 * v.y;
        __half2 hh = __floats2half2_rn(d1, d2);
        int b = d >> 6;
        int loc = atomicAdd(&cnt[b], 1);
        binned[(size_t)(base[b] + loc)] = make_int2(s | ((d & (BWID - 1)) << 16), *(int*)&hh);
    }
}

// ---------------------------------------------------------------------------
// K4: one block per bucket: per-dst count + LDS scan -> rowptr, then scatter
// into final dst-grouped CSR. csr entry = int2: { src, half2(edot1, edot2) }
__global__ __launch_bounds__(256) void build_kernel(const int* __restrict__ bstart,
                                                    const int2* __restrict__ binned,
                                                    int* __restrict__ rowptr,
                                                    int2* __restrict__ csr, int n) {
    __shared__ int cnt[BWID];
    __shared__ int sc[BWID];
    __shared__ int cur[BWID];
    int b = blockIdx.x, tid = threadIdx.x;
    int d0 = b << 6;
    int lo = bstart[b], hi = bstart[b + 1];
    if (tid < BWID) cnt[tid] = 0;
    __syncthreads();
    for (int k = lo + tid; k < hi; k += 256)
        atomicAdd(&cnt[(binned[k].x >> 16) & (BWID - 1)], 1);
    __syncthreads();
    if (tid < BWID) sc[tid] = cnt[tid];
    __syncthreads();
    for (int off = 1; off < BWID; off <<= 1) {
        int v = (tid < BWID && tid >= off) ? sc[tid - off] : 0;
        __syncthreads();
        if (tid < BWID) sc[tid] += v;
        __syncthreads();
    }
    if (tid < BWID) {
        int excl = sc[tid] - cnt[tid];
        cur[tid] = lo + excl;
        int d = d0 + tid;
        if (d < n) rowptr[d] = lo + excl;
    }
    __syncthreads();
    for (int k = lo + tid; k < hi; k += 256) {
        int2 e = binned[k];
        int slot = atomicAdd(&cur[(e.x >> 16) & (BWID - 1)], 1);
        csr[slot] = make_int2(e.x & 0xFFFF, e.y);
    }
}

// ---------------------------------------------------------------------------
// K6: fused GAT aggregation over 64-dim fp16 features (layer 1: feat = xh).
// Output t_out is fp16 [n x 64].  (r10-banked text — FROZEN, do not touch)
__global__ __launch_bounds__(256) void agg64_kernel(
        const int* __restrict__ rowptr, const int2* __restrict__ csr,
        const float* __restrict__ hs, const float* __restrict__ hd,
        const __half* __restrict__ feat, __half* __restrict__ t_out, int n) {
    int w = (blockIdx.x * blockDim.x + threadIdx.x) >> 6;
    int lane = threadIdx.x & 63;
    if (w >= n) return;
    int beg = rowptr[w], end = rowptr[w + 1];
    int len = end - beg;
    float hdv = hd[w], hsw = hs[w];
    int g = lane >> 4;      // 4 groups
    int c16 = lane & 15;    // 4-half chunk index within 64-wide row
    float4 acc = make_float4(0.f, 0.f, 0.f, 0.f);
    float m, scale, lself;

    if (len <= 64) {
        bool valid = lane < len;
        int2 c2 = valid ? csr[beg + lane] : make_int2(0, 0);
        __half2 dd = *(__half2*)&c2.y;
        float ed = valid ? __half2float(dd.x) : 0.f;
        float l = hs[c2.x] + hdv + ed;
        l = (l >= 0.f) ? l : 0.2f * l;
        float mymax = valid ? l : -1e30f;
        float edsum = ed;
        for (int off = 32; off; off >>= 1) {
            mymax = fmaxf(mymax, __shfl_xor(mymax, off));
            edsum += __shfl_xor(edsum, off);
        }
        lself = hsw + hdv + edsum / fmaxf((float)len, 1.0f);
        lself = (lself >= 0.f) ? lself : 0.2f * lself;
        m = fmaxf(mymax, lself);
        float p = valid ? __expf(l - m) : 0.f;
        float psum = p;
        for (int off = 32; off; off >>= 1) psum += __shfl_xor(psum, off);
        psum += __expf(lself - m);
        scale = 1.f / (psum + 1e-16f);
        float pn = p * scale;
        int src = c2.x;
        for (int j = g; j < len; j += 4) {
            float a = __shfl(pn, j);
            int sj = __shfl(src, j);
            float2 raw = *(const float2*)&feat[(size_t)sj * 64 + c16 * 4];
            __half2 h01 = *(__half2*)&raw.x;
            __half2 h23 = *(__half2*)&raw.y;
            float2 f01 = __half22float2(h01);
            float2 f23 = __half22float2(h23);
            acc.x += a * f01.x; acc.y += a * f01.y;
            acc.z += a * f23.x; acc.w += a * f23.y;
        }
    } else {
        float mymax = -1e30f, edsum = 0.f;
        for (int base = beg; base < end; base += 64) {
            int k = base + lane;
            if (k < end) {
                int2 c2 = csr[k];
                __half2 dd = *(__half2*)&c2.y;
                float ed = __half2float(dd.x);
                edsum += ed;
                float l = hs[c2.x] + hdv + ed;
                l = (l >= 0.f) ? l : 0.2f * l;
                mymax = fmaxf(mymax, l);
            }
        }
        for (int off = 32; off; off >>= 1) {
            mymax = fmaxf(mymax, __shfl_xor(mymax, off));
            edsum += __shfl_xor(edsum, off);
        }
        lself = hsw + hdv + edsum / fmaxf((float)len, 1.0f);
        lself = (lself >= 0.f) ? lself : 0.2f * lself;
        m = fmaxf(mymax, lself);
        float psum = 0.f;
        for (int base = beg; base < end; base += 64) {
            int k = base + lane;
            if (k < end) {
                int2 c2 = csr[k];
                __half2 dd = *(__half2*)&c2.y;
                float l = hs[c2.x] + hdv + __half2float(dd.x);
                l = (l >= 0.f) ? l : 0.2f * l;
                psum += __expf(l - m);
            }
        }
        for (int off = 32; off; off >>= 1) psum += __shfl_xor(psum, off);
        psum += __expf(lself - m);
        scale = 1.f / (psum + 1e-16f);
        for (int base = beg; base < end; base += 64) {
            int k = base + lane;
            float pn = 0.f; int src = 0;
            if (k < end) {
                int2 c2 = csr[k];
                __half2 dd = *(__half2*)&c2.y;
                float l = hs[c2.x] + hdv + __half2float(dd.x);
                l = (l >= 0.f) ? l : 0.2f * l;
                pn = __expf(l - m) * scale;
                src = c2.x;
            }
            int cl = min(end - base, 64);
            for (int j = g; j < cl; j += 4) {
                float a = __shfl(pn, j);
                int sj = __shfl(src, j);
                float2 raw = *(const float2*)&feat[(size_t)sj * 64 + c16 * 4];
                __half2 h01 = *(__half2*)&raw.x;
                __half2 h23 = *(__half2*)&raw.y;
                float2 f01 = __half22float2(h01);
                float2 f23 = __half22float2(h23);
                acc.x += a * f01.x; acc.y += a * f01.y;
                acc.z += a * f23.x; acc.w += a * f23.y;
            }
        }
    }
    if (g == 0) {  // self-loop
        float a = __expf(lself - m) * scale;
        float2 raw = *(const float2*)&feat[(size_t)w * 64 + c16 * 4];
        __half2 h01 = *(__half2*)&raw.x;
        __half2 h23 = *(__half2*)&raw.y;
        float2 f01 = __half22float2(h01);
        float2 f23 = __half22float2(h23);
        acc.x += a * f01.x; acc.y += a * f01.y;
        acc.z += a * f23.x; acc.w += a * f23.y;
    }
    // combine 4 group partials into lanes 0..15
    float4 p1, p2, p3;
    p1.x = __shfl(acc.x, c16 + 16); p1.y = __shfl(acc.y, c16 + 16);
    p1.z = __shfl(acc.z, c16 + 16); p1.w = __shfl(acc.w, c16 + 16);
    p2.x = __shfl(acc.x, c16 + 32); p2.y = __shfl(acc.y, c16 + 32);
    p2.z = __shfl(acc.z, c16 + 32); p2.w = __shfl(acc.w, c16 + 32);
    p3.x = __shfl(acc.x, c16 + 48); p3.y = __shfl(acc.y, c16 + 48);
    p3.z = __shfl(acc.z, c16 + 48); p3.w = __shfl(acc.w, c16 + 48);
    if (lane < 16) {
        float4 o;
        o.x = acc.x + p1.x + p2.x + p3.x;
        o.y = acc.y + p1.y + p2.y + p3.y;
        o.z = acc.z + p1.z + p2.z + p3.z;
        o.w = acc.w + p1.w + p2.w + p3.w;
        __half2 q0 = __floats2half2_rn(o.x, o.y);
        __half2 q1 = __floats2half2_rn(o.z, o.w);
        int2 st; st.x = *(int*)&q0; st.y = *(int*)&q1;
        *(int2*)&t_out[(size_t)w * 64 + c16 * 4] = st;
    }
}

// ---------------------------------------------------------------------------
// K7: fused GAT aggregation over 128-dim fp16 features (layer 2: feat = out1h).
// Output t_out is fp16 [n x 128].  (r10-banked text — FROZEN, do not touch)
__global__ __launch_bounds__(256) void agg128_kernel(
        const int* __restrict__ rowptr, const int2* __restrict__ csr,
        const float* __restrict__ hs, const float* __restrict__ hd,
        const __half* __restrict__ feat, __half* __restrict__ t_out, int n) {
    int w = (blockIdx.x * blockDim.x + threadIdx.x) >> 6;
    int lane = threadIdx.x & 63;
    if (w >= n) return;
    int beg = rowptr[w], end = rowptr[w + 1];
    int len = end - beg;
    float hdv = hd[w], hsw = hs[w];
    int half = lane >> 5;
    int col = lane & 31;
    float4 acc = make_float4(0.f, 0.f, 0.f, 0.f);
    float m, scale, lself;

    if (len <= 64) {
        bool valid = lane < len;
        int2 c2 = valid ? csr[beg + lane] : make_int2(0, 0);
        __half2 dd = *(__half2*)&c2.y;
        float ed = valid ? __half2float(dd.y) : 0.f;
        float l = hs[c2.x] + hdv + ed;
        l = (l >= 0.f) ? l : 0.2f * l;
        float mymax = valid ? l : -1e30f;
        float edsum = ed;
        for (int off = 32; off; off >>= 1) {
            mymax = fmaxf(mymax, __shfl_xor(mymax, off));
            edsum += __shfl_xor(edsum, off);
        }
        lself = hsw + hdv + edsum / fmaxf((float)len, 1.0f);
        lself = (lself >= 0.f) ? lself : 0.2f * lself;
        m = fmaxf(mymax, lself);
        float p = valid ? __expf(l - m) : 0.f;
        float psum = p;
        for (int off = 32; off; off >>= 1) psum += __shfl_xor(psum, off);
        psum += __expf(lself - m);
        scale = 1.f / (psum + 1e-16f);
        float pn = p * scale;
        int src = c2.x;
        for (int j = half; j < len; j += 2) {
            float a = __shfl(pn, j);
            int sj = __shfl(src, j);
            float2 raw = *(const float2*)&feat[(size_t)sj * H_DIM + col * 4];
            __half2 h01 = *(__half2*)&raw.x;
            __half2 h23 = *(__half2*)&raw.y;
            float2 f01 = __half22float2(h01);
            float2 f23 = __half22float2(h23);
            acc.x += a * f01.x; acc.y += a * f01.y;
            acc.z += a * f23.x; acc.w += a * f23.y;
        }
    } else {
        float mymax = -1e30f, edsum = 0.f;
        for (int base = beg; base < end; base += 64) {
            int k = base + lane;
            if (k < end) {
                int2 c2 = csr[k];
                __half2 dd = *(__half2*)&c2.y;
                float ed = __half2float(dd.y);
                edsum += ed;
                float l = hs[c2.x] + hdv + ed;
                l = (l >= 0.f) ? l : 0.2f * l;
                mymax = fmaxf(mymax, l);
            }
        }
        for (int off = 32; off; off >>= 1) {
            mymax = fmaxf(mymax, __shfl_xor(mymax, off));
            edsum += __shfl_xor(edsum, off);
        }
        lself = hsw + hdv + edsum / fmaxf((float)len, 1.0f);
        lself = (lself >= 0.f) ? lself : 0.2f * lself;
        m = fmaxf(mymax, lself);
        float psum = 0.f;
        for (int base = beg; base < end; base += 64) {
            int k = base + lane;
            if (k < end) {
                int2 c2 = csr[k];
                __half2 dd = *(__half2*)&c2.y;
                float l = hs[c2.x] + hdv + __half2float(dd.y);
                l = (l >= 0.f) ? l : 0.2f * l;
                psum += __expf(l - m);
            }
        }
        for (int off = 32; off; off >>= 1) psum += __shfl_xor(psum, off);
        psum += __expf(lself - m);
        scale = 1.f / (psum + 1e-16f);
        for (int base = beg; base < end; base += 64) {
            int k = base + lane;
            float pn = 0.f; int src = 0;
            if (k < end) {
                int2 c2 = csr[k];
                __half2 dd = *(__half2*)&c2.y;
                float l = hs[c2.x] + hdv + __half2float(dd.y);
                l = (l >= 0.f) ? l : 0.2f * l;
                pn = __expf(l - m) * scale;
                src = c2.x;
            }
            int cl = min(end - base, 64);
            for (int j = half; j < cl; j += 2) {
                float a = __shfl(pn, j);
                int sj = __shfl(src, j);
                float2 raw = *(const float2*)&feat[(size_t)sj * H_DIM + col * 4];
                __half2 h01 = *(__half2*)&raw.x;
                __half2 h23 = *(__half2*)&raw.y;
                float2 f01 = __half22float2(h01);
                float2 f23 = __half22float2(h23);
                acc.x += a * f01.x; acc.y += a * f01.y;
                acc.z += a * f23.x; acc.w += a * f23.y;
            }
        }
    }
    if (half == 0) {  // self-loop
        float a = __expf(lself - m) * scale;
        float2 raw = *(const float2*)&feat[(size_t)w * H_DIM + col * 4];
        __half2 h01 = *(__half2*)&raw.x;
        __half2 h23 = *(__half2*)&raw.y;
        float2 f01 = __half22float2(h01);
        float2 f23 = __half22float2(h23);
        acc.x += a * f01.x; acc.y += a * f01.y;
        acc.z += a * f23.x; acc.w += a * f23.y;
    }
    float4 oth;
    oth.x = __shfl(acc.x, col + 32);
    oth.y = __shfl(acc.y, col + 32);
    oth.z = __shfl(acc.z, col + 32);
    oth.w = __shfl(acc.w, col + 32);
    if (half == 0) {
        float4 o;
        o.x = acc.x + oth.x; o.y = acc.y + oth.y;
        o.z = acc.z + oth.z; o.w = acc.w + oth.w;
        __half2 q0 = __floats2half2_rn(o.x, o.y);
        __half2 q1 = __floats2half2_rn(o.z, o.w);
        int2 st; st.x = *(int*)&q0; st.y = *(int*)&q1;
        *(int2*)&t_out[(size_t)w * H_DIM + col * 4] = st;
    }
}

// ---------------------------------------------------------------------------
// K8: out = relu(T @ W + b); T is fp16.
// DO_HSHD: epilogue hs/hd for the NEXT layer.
// DO_POOL: skip the global store entirely; instead accumulate per-block fp32
//          column sums in LDS and atomicAdd 128 floats to pooled.
template <int FIN, bool DO_HSHD, bool OUT_HALF, bool DO_POOL>
__global__ __launch_bounds__(256) void gemm_kernel(const __half* __restrict__ X,
                                                   const float* __restrict__ W,
                                                   const float* __restrict__ bias,
                                                   const float* __restrict__ vs,
                                                   const float* __restrict__ vd,
                                                   void* __restrict__ HoutV,
                                                   float* __restrict__ hs,
                                                   float* __restrict__ hd,
                                                   float* __restrict__ pooled, int n) {
    __shared__ float xs[32 * FIN];
    __shared__ float psum[DO_POOL ? 128 : 1];
    int tid = threadIdx.x;
    int r0 = blockIdx.x * 32;
    if (DO_POOL && tid < 128) psum[tid] = 0.f;
    constexpr int NV = 32 * FIN / 8;  // 8 halfs (16B) per staging load
    for (int idx = tid; idx < NV; idx += 256) {
        int r = (idx * 8) / FIN, k = idx * 8 - r * FIN;
        int row = r0 + r;
        float* p = &xs[r * FIN + k];
        if (row < n) {
            int4 raw = *(const int4*)&X[(size_t)row * FIN + k];
            __half2 h0 = *(__half2*)&raw.x;
            __half2 h1 = *(__half2*)&raw.y;
            __half2 h2 = *(__half2*)&raw.z;
            __half2 h3 = *(__half2*)&raw.w;
            float2 f0 = __half22float2(h0), f1 = __half22float2(h1);
            float2 f2 = __half22float2(h2), f3 = __half22float2(h3);
            p[0] = f0.x; p[1] = f0.y; p[2] = f1.x; p[3] = f1.y;
            p[4] = f2.x; p[5] = f2.y; p[6] = f3.x; p[7] = f3.y;
        } else {
#pragma unroll
            for (int q = 0; q < 8; ++q) p[q] = 0.f;
        }
    }
    __syncthreads();
    int tcol = tid & 31;   // cols 4*tcol .. +3
    int trow = tid >> 5;   // rows 4*trow .. +3
    float acc[4][4] = {{0.f}};
    const float* wp = W + tcol * 4;
    const float* x0p = &xs[(trow * 4 + 0) * FIN];
    const float* x1p = &xs[(trow * 4 + 1) * FIN];
    const float* x2p = &xs[(trow * 4 + 2) * FIN];
    const float* x3p = &xs[(trow * 4 + 3) * FIN];
#pragma unroll 8
    for (int k = 0; k < FIN; ++k) {
        float4 w4 = *(const float4*)(wp + k * H_DIM);
        float x0 = x0p[k], x1 = x1p[k], x2 = x2p[k], x3 = x3p[k];
        acc[0][0] += x0 * w4.x; acc[0][1] += x0 * w4.y; acc[0][2] += x0 * w4.z; acc[0][3] += x0 * w4.w;
        acc[1][0] += x1 * w4.x; acc[1][1] += x1 * w4.y; acc[1][2] += x1 * w4.z; acc[1][3] += x1 * w4.w;
        acc[2][0] += x2 * w4.x; acc[2][1] += x2 * w4.y; acc[2][2] += x2 * w4.z; acc[2][3] += x2 * w4.w;
        acc[3][0] += x3 * w4.x; acc[3][1] += x3 * w4.y; acc[3][2] += x3 * w4.z; acc[3][3] += x3 * w4.w;
    }
    float4 b4 = *(const float4*)&bias[tcol * 4];
    float4 vs4, vd4;
    if (DO_HSHD) {
        vs4 = *(const float4*)&vs[tcol * 4];
        vd4 = *(const float4*)&vd[tcol * 4];
    }
    float cps0 = 0.f, cps1 = 0.f, cps2 = 0.f, cps3 = 0.f;
#pragma unroll
    for (int r = 0; r < 4; ++r) {
        int row = r0 + trow * 4 + r;
        float4 o;
        o.x = fmaxf(acc[r][0] + b4.x, 0.f);
        o.y = fmaxf(acc[r][1] + b4.y, 0.f);
        o.z = fmaxf(acc[r][2] + b4.z, 0.f);
        o.w = fmaxf(acc[r][3] + b4.w, 0.f);
        if (row < n) {
            if (DO_POOL) {
                cps0 += o.x; cps1 += o.y; cps2 += o.z; cps3 += o.w;
            } else if (OUT_HALF) {
                __half2 q0 = __floats2half2_rn(o.x, o.y);
                __half2 q1 = __floats2half2_rn(o.z, o.w);
                int2 st; st.x = *(int*)&q0; st.y = *(int*)&q1;
                *(int2*)((__half*)HoutV + (size_t)row * H_DIM + tcol * 4) = st;
            } else {
                *(float4*)((float*)HoutV + (size_t)row * H_DIM + tcol * 4) = o;
            }
        }
        if (DO_HSHD) {
            float ss = o.x * vs4.x + o.y * vs4.y + o.z * vs4.z + o.w * vs4.w;
            float sd = o.x * vd4.x + o.y * vd4.y + o.z * vd4.z + o.w * vd4.w;
            for (int off = 16; off; off >>= 1) {
                ss += __shfl_xor(ss, off);
                sd += __shfl_xor(sd, off);
            }
            if (tcol == 0 && row < n) { hs[row] = ss; hd[row] = sd; }
        }
    }
    if (DO_POOL) {
        atomicAdd(&psum[tcol * 4 + 0], cps0);
        atomicAdd(&psum[tcol * 4 + 1], cps1);
        atomicAdd(&psum[tcol * 4 + 2], cps2);
        atomicAdd(&psum[tcol * 4 + 3], cps3);
        __syncthreads();
        if (tid < 128) atomicAdd(&pooled[tid], psum[tid]);
    }
}

// ---------------------------------------------------------------------------
// K10: out = tanh(mean(h) @ Wfc + bfc)
__global__ void final_kernel(const float* __restrict__ pooled, const float* __restrict__ Wfc,
                             const float* __restrict__ bfc, float* __restrict__ out, int n) {
    int t = threadIdx.x;
    if (t >= 16) return;
    float inv_n = 1.0f / (float)n;
    float s = 0.f;
    for (int j = 0; j < 128; ++j) s += pooled[j] * inv_n * Wfc[j * 16 + t];
    out[t] = tanhf(s + bfc[t]);
}

// ---------------------------------------------------------------------------
extern "C" void kernel_launch(void* const* d_in, const int* in_sizes, int n_in,
                              void* d_out, int out_size, void* d_ws, size_t ws_size,
                              hipStream_t stream) {
    const float* x   = (const float*)d_in[0];
    const int*   ei  = (const int*)d_in[1];
    const float* ea  = (const float*)d_in[2];
    const float* W1  = (const float*)d_in[3];
    const float* We1 = (const float*)d_in[4];
    const float* as1 = (const float*)d_in[5];
    const float* ad1 = (const float*)d_in[6];
    const float* ae1 = (const float*)d_in[7];
    const float* b1  = (const float*)d_in[8];
    const float* W2  = (const float*)d_in[9];
    const float* We2 = (const float*)d_in[10];
    const float* as2 = (const float*)d_in[11];
    const float* ad2 = (const float*)d_in[12];
    const float* ae2 = (const float*)d_in[13];
    const float* b2  = (const float*)d_in[14];
    const float* Wfc = (const float*)d_in[15];
    const float* bfc = (const float*)d_in[16];
    float* out = (float*)d_out;

    const int n = in_sizes[0] / 64;      // 50000
    const int E = in_sizes[1] / 2;       // 1600000
    const int B = (n + BWID - 1) / BWID; // 782 buckets

    // workspace layout (float units, 256B-aligned blocks).
    // gcnt and pool are FIRST and contiguous -> one memset covers both.
    size_t o = 0;
    auto alloc = [&](size_t count) { size_t r = o; o += (count + 63) & ~(size_t)63; return r; };
    size_t o_gcnt   = alloc(BMAX);                // int   (1024)
    size_t o_pool   = alloc(128);                 // float (contiguous after gcnt)
    size_t o_bstart = alloc(BMAX + 1);            // int
    size_t o_gcur   = alloc(BMAX);                // int
    size_t o_rowptr = alloc(n + 1);               // int
    size_t o_csr    = alloc(2 * (size_t)E);       // int2 per edge (12.8MB)
    size_t o_bufA   = alloc((size_t)n * H_DIM);   // binned int2 (early only)
    size_t o_xh     = alloc((size_t)n * 32);      // x in fp16  (n x 64 half)
    size_t o_t1h    = alloc((size_t)n * 32);      // t1 fp16    (n x 64 half)
    size_t o_o1h    = alloc((size_t)n * 64);      // out1 fp16  (n x 128 half)
    size_t o_t2h    = alloc((size_t)n * 64);      // t2 fp16    (n x 128 half)
    size_t o_hs     = alloc(n);
    size_t o_hd     = alloc(n);
    size_t o_c      = alloc(4);
    size_t o_vs1    = alloc(64);
    size_t o_vd1    = alloc(64);
    size_t o_vs2    = alloc(128);
    size_t o_vd2    = alloc(128);
    (void)ws_size;
    float* wsf = (float*)d_ws;
    int2* binned = (int2*)(wsf + o_bufA);
    int2* csr2   = (int2*)(wsf + o_csr);

    // single memset: gcnt (BMAX ints) + pool (128 floats), contiguous
    hipMemsetAsync(wsf + o_gcnt, 0, (BMAX + 128) * sizeof(int), stream);

    int ebg = (E + CHUNK - 1) / CHUNK;  // edge-chunk grid (782)
    int wgrid = (n + 3) / 4;            // 4 waves (nodes) per 256-thread block

    // fused prep | count (last block = prep)
    prep_count_kernel<<<ebg + 1, 256, 0, stream>>>(We1, ae1, We2, ae2,
        W1, as1, ad1, W2, as2, ad2,
        wsf + o_c, wsf + o_vs1, wsf + o_vd1, wsf + o_vs2, wsf + o_vd2,
        ei, (int*)(wsf + o_gcnt), E, B, ebg);
    bscan_kernel<<<1, BMAX, 0, stream>>>((int*)(wsf + o_gcnt), (int*)(wsf + o_bstart),
        (int*)(wsf + o_gcur), (int*)(wsf + o_rowptr), B, n, E);
    // fused bin | hshd64 (blocks >= ebg do hshd)
    bin_hshd_kernel<<<ebg + wgrid, 256, 0, stream>>>(ei, ea, wsf + o_c,
        (int*)(wsf + o_gcur), binned, E, B, ebg,
        x, wsf + o_vs1, wsf + o_vd1, wsf + o_hs, wsf + o_hd,
        (__half*)(wsf + o_xh), n);
    build_kernel<<<B, 256, 0, stream>>>((int*)(wsf + o_bstart), binned,
        (int*)(wsf + o_rowptr), csr2, n);

    // ---- layer 1 (aggregate xh fp16, then GEMM -> out1 fp16) ----
    agg64_kernel<<<wgrid, 256, 0, stream>>>((int*)(wsf + o_rowptr), csr2,
        wsf + o_hs, wsf + o_hd, (const __half*)(wsf + o_xh), (__half*)(wsf + o_t1h), n);
    gemm_kernel<64, true, true, false><<<(n + 31) / 32, 256, 0, stream>>>(
        (const __half*)(wsf + o_t1h), W1, b1, wsf + o_vs2, wsf + o_vd2,
        (void*)(wsf + o_o1h), wsf + o_hs, wsf + o_hd, nullptr, n);

    // ---- layer 2 (aggregate out1 fp16, then GEMM with fused mean-pool) ----
    agg128_kernel<<<wgrid, 256, 0, stream>>>((int*)(wsf + o_rowptr), csr2,
        wsf + o_hs, wsf + o_hd, (const __half*)(wsf + o_o1h), (__half*)(wsf + o_t2h), n);
    gemm_kernel<128, false, true, true><<<(n + 31) / 32, 256, 0, stream>>>(
        (const __half*)(wsf + o_t2h), W2, b2, nullptr, nullptr,
        nullptr, nullptr, nullptr, wsf + o_pool, n);

    // ---- head ----
    final_kernel<<<1, 64, 0, stream>>>(wsf + o_pool, Wfc, bfc, out, n);
}

// Round 14
// 363.258 us; speedup vs baseline: 1.0355x; 1.0355x over previous
//
#include <hip/hip_runtime.h>
#include <hip/hip_fp16.h>
#include <math.h>

// Problem constants: N=50000, E=1600000, F=64, H=128, ED=2, A=16
// NOTE: src-index packing below requires n < 65536 (n=50000 here).
#define H_DIM 128
#define BWID 128      // dsts per bucket (bucket = dst >> 7)
#define BMAX 512      // max buckets (n <= 65536)
#define CHUNK 4096    // edges per block in count/bin

// ---------------------------------------------------------------------------
// K0a: fused {prep | count}. Last block does the tiny precomputes:
//   c[0..3] = We^T @ a_edge; vs1/vd1 = W1 @ a_s/a_d; vs2/vd2 = W2 @ a_s/a_d.
// All other blocks do the bucket histogram (LDS pre-aggregated).
__global__ __launch_bounds__(256) void prep_count_kernel(
        const float* __restrict__ We1, const float* __restrict__ ae1,
        const float* __restrict__ We2, const float* __restrict__ ae2,
        const float* __restrict__ W1, const float* __restrict__ as1,
        const float* __restrict__ ad1,
        const float* __restrict__ W2, const float* __restrict__ as2,
        const float* __restrict__ ad2,
        float* __restrict__ c, float* __restrict__ vs1,
        float* __restrict__ vd1, float* __restrict__ vs2,
        float* __restrict__ vd2,
        const int* __restrict__ ei, int* __restrict__ gcnt,
        int E, int B, int ebg) {
    int t = threadIdx.x;
    if ((int)blockIdx.x == ebg) {
        if (t < 64) {
            float s = 0.f, d = 0.f;
            for (int h = 0; h < 128; ++h) {
                float w = W1[t * 128 + h];
                s += w * as1[h];
                d += w * ad1[h];
            }
            vs1[t] = s; vd1[t] = d;
        } else if (t < 192) {
            int k = t - 64;
            float s = 0.f, d = 0.f;
            for (int h = 0; h < 128; ++h) {
                float w = W2[k * 128 + h];
                s += w * as2[h];
                d += w * ad2[h];
            }
            vs2[k] = s; vd2[k] = d;
        } else {
            int l = t - 192;  // lane of wave 3
            float a1x = ae1[l], a1y = ae1[l + 64];
            float a2x = ae2[l], a2y = ae2[l + 64];
            float v0 = We1[l] * a1x + We1[l + 64] * a1y;
            float v1 = We1[128 + l] * a1x + We1[192 + l] * a1y;
            float v2 = We2[l] * a2x + We2[l + 64] * a2y;
            float v3 = We2[128 + l] * a2x + We2[192 + l] * a2y;
            for (int off = 32; off; off >>= 1) {
                v0 += __shfl_xor(v0, off);
                v1 += __shfl_xor(v1, off);
                v2 += __shfl_xor(v2, off);
                v3 += __shfl_xor(v3, off);
            }
            if (l == 0) { c[0] = v0; c[1] = v1; c[2] = v2; c[3] = v3; }
        }
        return;
    }
    __shared__ int hist[BMAX];
    for (int i = t; i < B; i += 256) hist[i] = 0;
    __syncthreads();
    int lo = blockIdx.x * CHUNK, hi = min(lo + CHUNK, E);
    for (int e = lo + t; e < hi; e += 256)
        atomicAdd(&hist[ei[E + e] >> 7], 1);
    __syncthreads();
    for (int i = t; i < B; i += 256)
        if (hist[i]) atomicAdd(&gcnt[i], hist[i]);
}

// ---------------------------------------------------------------------------
// K2: scan bucket counts -> bstart (excl prefix), seed gcur, write tails
__global__ void bscan_kernel(const int* __restrict__ gcnt, int* __restrict__ bstart,
                             int* __restrict__ gcur, int* __restrict__ rowptr,
                             int B, int n, int E) {
    __shared__ int s[BMAX];
    int t = threadIdx.x;  // 512 threads
    int v0 = (t < B) ? gcnt[t] : 0;
    s[t] = v0;
    __syncthreads();
    for (int off = 1; off < BMAX; off <<= 1) {
        int v = (t >= off) ? s[t - off] : 0;
        __syncthreads();
        s[t] += v;
        __syncthreads();
    }
    if (t < B) {
        int excl = s[t] - v0;
        bstart[t] = excl;
        gcur[t] = excl;
    }
    if (t == 0) { bstart[B] = E; rowptr[n] = E; }
}

// ---------------------------------------------------------------------------
// K3: fused {bin | hshd64}. Blocks [0, ebg) bin edges by bucket;
// blocks [ebg, ebg+wgrid) compute hs/hd + x->fp16 conversion.
__global__ __launch_bounds__(256) void bin_hshd_kernel(
        const int* __restrict__ ei, const float* __restrict__ ea,
        const float* __restrict__ cvec, int* __restrict__ gcur,
        int2* __restrict__ binned, int E, int B, int ebg,
        const float* __restrict__ x, const float* __restrict__ vs,
        const float* __restrict__ vd, float* __restrict__ hs,
        float* __restrict__ hd, __half* __restrict__ xh, int n) {
    int tid = threadIdx.x;
    if ((int)blockIdx.x >= ebg) {
        int w = (((int)blockIdx.x - ebg) * 256 + tid) >> 6;
        int lane = tid & 63;
        if (w >= n) return;
        float xv = x[(size_t)w * 64 + lane];
        xh[(size_t)w * 64 + lane] = __float2half(xv);
        float ss = xv * vs[lane];
        float sd = xv * vd[lane];
        for (int off = 32; off; off >>= 1) {
            ss += __shfl_xor(ss, off);
            sd += __shfl_xor(sd, off);
        }
        if (lane == 0) { hs[w] = ss; hd[w] = sd; }
        return;
    }
    __shared__ int cnt[BMAX];
    __shared__ int base[BMAX];
    for (int i = tid; i < B; i += 256) cnt[i] = 0;
    __syncthreads();
    int lo = blockIdx.x * CHUNK, hi = min(lo + CHUNK, E);
    for (int e = lo + tid; e < hi; e += 256)
        atomicAdd(&cnt[ei[E + e] >> 7], 1);
    __syncthreads();
    for (int i = tid; i < B; i += 256) {
        int c = cnt[i];
        base[i] = c ? atomicAdd(&gcur[i], c) : 0;
        cnt[i] = 0;  // reuse as local cursor
    }
    __syncthreads();
    float c0 = cvec[0], c1 = cvec[1], c2 = cvec[2], c3 = cvec[3];
    for (int e = lo + tid; e < hi; e += 256) {
        int s = ei[e], d = ei[E + e];
        float2 v = ((const float2*)ea)[e];
        float d1 = c0 * v.x + c1 * v.y;
        float d2 = c2 * v.x + c3 * v.y;
        __half2 hh = __floats2half2_rn(d1, d2);
        int b = d >> 7;
        int loc = atomicAdd(&cnt[b], 1);
        binned[(size_t)(base[b] + loc)] = make_int2(s | ((d & 127) << 16), *(int*)&hh);
    }
}

// ---------------------------------------------------------------------------
// K4: one block per bucket: per-dst count + LDS scan -> rowptr, then scatter
// into final dst-grouped CSR. csr entry = int2: { src, half2(edot1, edot2) }
__global__ __launch_bounds__(256) void build_kernel(const int* __restrict__ bstart,
                                                    const int2* __restrict__ binned,
                                                    int* __restrict__ rowptr,
                                                    int2* __restrict__ csr, int n) {
    __shared__ int cnt[BWID];
    __shared__ int sc[BWID];
    __shared__ int cur[BWID];
    int b = blockIdx.x, tid = threadIdx.x;
    int d0 = b << 7;
    int lo = bstart[b], hi = bstart[b + 1];
    if (tid < BWID) cnt[tid] = 0;
    __syncthreads();
    for (int k = lo + tid; k < hi; k += 256)
        atomicAdd(&cnt[(binned[k].x >> 16) & (BWID - 1)], 1);
    __syncthreads();
    if (tid < BWID) sc[tid] = cnt[tid];
    __syncthreads();
    for (int off = 1; off < BWID; off <<= 1) {
        int v = (tid < BWID && tid >= off) ? sc[tid - off] : 0;
        __syncthreads();
        if (tid < BWID) sc[tid] += v;
        __syncthreads();
    }
    if (tid < BWID) {
        int excl = sc[tid] - cnt[tid];
        cur[tid] = lo + excl;
        int d = d0 + tid;
        if (d < n) rowptr[d] = lo + excl;
    }
    __syncthreads();
    for (int k = lo + tid; k < hi; k += 256) {
        int2 e = binned[k];
        int slot = atomicAdd(&cur[(e.x >> 16) & (BWID - 1)], 1);
        csr[slot] = make_int2(e.x & 0xFFFF, e.y);
    }
}

// ---------------------------------------------------------------------------
// K6: fused GAT aggregation over 64-dim fp16 features (layer 1: feat = xh).
// Output t_out is fp16 [n x 64].  (r10-banked text — FROZEN, do not touch)
__global__ __launch_bounds__(256) void agg64_kernel(
        const int* __restrict__ rowptr, const int2* __restrict__ csr,
        const float* __restrict__ hs, const float* __restrict__ hd,
        const __half* __restrict__ feat, __half* __restrict__ t_out, int n) {
    int w = (blockIdx.x * blockDim.x + threadIdx.x) >> 6;
    int lane = threadIdx.x & 63;
    if (w >= n) return;
    int beg = rowptr[w], end = rowptr[w + 1];
    int len = end - beg;
    float hdv = hd[w], hsw = hs[w];
    int g = lane >> 4;      // 4 groups
    int c16 = lane & 15;    // 4-half chunk index within 64-wide row
    float4 acc = make_float4(0.f, 0.f, 0.f, 0.f);
    float m, scale, lself;

    if (len <= 64) {
        bool valid = lane < len;
        int2 c2 = valid ? csr[beg + lane] : make_int2(0, 0);
        __half2 dd = *(__half2*)&c2.y;
        float ed = valid ? __half2float(dd.x) : 0.f;
        float l = hs[c2.x] + hdv + ed;
        l = (l >= 0.f) ? l : 0.2f * l;
        float mymax = valid ? l : -1e30f;
        float edsum = ed;
        for (int off = 32; off; off >>= 1) {
            mymax = fmaxf(mymax, __shfl_xor(mymax, off));
            edsum += __shfl_xor(edsum, off);
        }
        lself = hsw + hdv + edsum / fmaxf((float)len, 1.0f);
        lself = (lself >= 0.f) ? lself : 0.2f * lself;
        m = fmaxf(mymax, lself);
        float p = valid ? __expf(l - m) : 0.f;
        float psum = p;
        for (int off = 32; off; off >>= 1) psum += __shfl_xor(psum, off);
        psum += __expf(lself - m);
        scale = 1.f / (psum + 1e-16f);
        float pn = p * scale;
        int src = c2.x;
        for (int j = g; j < len; j += 4) {
            float a = __shfl(pn, j);
            int sj = __shfl(src, j);
            float2 raw = *(const float2*)&feat[(size_t)sj * 64 + c16 * 4];
            __half2 h01 = *(__half2*)&raw.x;
            __half2 h23 = *(__half2*)&raw.y;
            float2 f01 = __half22float2(h01);
            float2 f23 = __half22float2(h23);
            acc.x += a * f01.x; acc.y += a * f01.y;
            acc.z += a * f23.x; acc.w += a * f23.y;
        }
    } else {
        float mymax = -1e30f, edsum = 0.f;
        for (int base = beg; base < end; base += 64) {
            int k = base + lane;
            if (k < end) {
                int2 c2 = csr[k];
                __half2 dd = *(__half2*)&c2.y;
                float ed = __half2float(dd.x);
                edsum += ed;
                float l = hs[c2.x] + hdv + ed;
                l = (l >= 0.f) ? l : 0.2f * l;
                mymax = fmaxf(mymax, l);
            }
        }
        for (int off = 32; off; off >>= 1) {
            mymax = fmaxf(mymax, __shfl_xor(mymax, off));
            edsum += __shfl_xor(edsum, off);
        }
        lself = hsw + hdv + edsum / fmaxf((float)len, 1.0f);
        lself = (lself >= 0.f) ? lself : 0.2f * lself;
        m = fmaxf(mymax, lself);
        float psum = 0.f;
        for (int base = beg; base < end; base += 64) {
            int k = base + lane;
            if (k < end) {
                int2 c2 = csr[k];
                __half2 dd = *(__half2*)&c2.y;
                float l = hs[c2.x] + hdv + __half2float(dd.x);
                l = (l >= 0.f) ? l : 0.2f * l;
                psum += __expf(l - m);
            }
        }
        for (int off = 32; off; off >>= 1) psum += __shfl_xor(psum, off);
        psum += __expf(lself - m);
        scale = 1.f / (psum + 1e-16f);
        for (int base = beg; base < end; base += 64) {
            int k = base + lane;
            float pn = 0.f; int src = 0;
            if (k < end) {
                int2 c2 = csr[k];
                __half2 dd = *(__half2*)&c2.y;
                float l = hs[c2.x] + hdv + __half2float(dd.x);
                l = (l >= 0.f) ? l : 0.2f * l;
                pn = __expf(l - m) * scale;
                src = c2.x;
            }
            int cl = min(end - base, 64);
            for (int j = g; j < cl; j += 4) {
                float a = __shfl(pn, j);
                int sj = __shfl(src, j);
                float2 raw = *(const float2*)&feat[(size_t)sj * 64 + c16 * 4];
                __half2 h01 = *(__half2*)&raw.x;
                __half2 h23 = *(__half2*)&raw.y;
                float2 f01 = __half22float2(h01);
                float2 f23 = __half22float2(h23);
                acc.x += a * f01.x; acc.y += a * f01.y;
                acc.z += a * f23.x; acc.w += a * f23.y;
            }
        }
    }
    if (g == 0) {  // self-loop
        float a = __expf(lself - m) * scale;
        float2 raw = *(const float2*)&feat[(size_t)w * 64 + c16 * 4];
        __half2 h01 = *(__half2*)&raw.x;
        __half2 h23 = *(__half2*)&raw.y;
        float2 f01 = __half22float2(h01);
        float2 f23 = __half22float2(h23);
        acc.x += a * f01.x; acc.y += a * f01.y;
        acc.z += a * f23.x; acc.w += a * f23.y;
    }
    // combine 4 group partials into lanes 0..15
    float4 p1, p2, p3;
    p1.x = __shfl(acc.x, c16 + 16); p1.y = __shfl(acc.y, c16 + 16);
    p1.z = __shfl(acc.z, c16 + 16); p1.w = __shfl(acc.w, c16 + 16);
    p2.x = __shfl(acc.x, c16 + 32); p2.y = __shfl(acc.y, c16 + 32);
    p2.z = __shfl(acc.z, c16 + 32); p2.w = __shfl(acc.w, c16 + 32);
    p3.x = __shfl(acc.x, c16 + 48); p3.y = __shfl(acc.y, c16 + 48);
    p3.z = __shfl(acc.z, c16 + 48); p3.w = __shfl(acc.w, c16 + 48);
    if (lane < 16) {
        float4 o;
        o.x = acc.x + p1.x + p2.x + p3.x;
        o.y = acc.y + p1.y + p2.y + p3.y;
        o.z = acc.z + p1.z + p2.z + p3.z;
        o.w = acc.w + p1.w + p2.w + p3.w;
        __half2 q0 = __floats2half2_rn(o.x, o.y);
        __half2 q1 = __floats2half2_rn(o.z, o.w);
        int2 st; st.x = *(int*)&q0; st.y = *(int*)&q1;
        *(int2*)&t_out[(size_t)w * 64 + c16 * 4] = st;
    }
}

// ---------------------------------------------------------------------------
// K7: fused GAT aggregation over 128-dim fp16 features (layer 2: feat = out1h).
// Output t_out is fp16 [n x 128].  (r10-banked text — FROZEN, do not touch)
__global__ __launch_bounds__(256) void agg128_kernel(
        const int* __restrict__ rowptr, const int2* __restrict__ csr,
        const float* __restrict__ hs, const float* __restrict__ hd,
        const __half* __restrict__ feat, __half* __restrict__ t_out, int n) {
    int w = (blockIdx.x * blockDim.x + threadIdx.x) >> 6;
    int lane = threadIdx.x & 63;
    if (w >= n) return;
    int beg = rowptr[w], end = rowptr[w + 1];
    int len = end - beg;
    float hdv = hd[w], hsw = hs[w];
    int half = lane >> 5;
    int col = lane & 31;
    float4 acc = make_float4(0.f, 0.f, 0.f, 0.f);
    float m, scale, lself;

    if (len <= 64) {
        bool valid = lane < len;
        int2 c2 = valid ? csr[beg + lane] : make_int2(0, 0);
        __half2 dd = *(__half2*)&c2.y;
        float ed = valid ? __half2float(dd.y) : 0.f;
        float l = hs[c2.x] + hdv + ed;
        l = (l >= 0.f) ? l : 0.2f * l;
        float mymax = valid ? l : -1e30f;
        float edsum = ed;
        for (int off = 32; off; off >>= 1) {
            mymax = fmaxf(mymax, __shfl_xor(mymax, off));
            edsum += __shfl_xor(edsum, off);
        }
        lself = hsw + hdv + edsum / fmaxf((float)len, 1.0f);
        lself = (lself >= 0.f) ? lself : 0.2f * lself;
        m = fmaxf(mymax, lself);
        float p = valid ? __expf(l - m) : 0.f;
        float psum = p;
        for (int off = 32; off; off >>= 1) psum += __shfl_xor(psum, off);
        psum += __expf(lself - m);
        scale = 1.f / (psum + 1e-16f);
        float pn = p * scale;
        int src = c2.x;
        for (int j = half; j < len; j += 2) {
            float a = __shfl(pn, j);
            int sj = __shfl(src, j);
            float2 raw = *(const float2*)&feat[(size_t)sj * H_DIM + col * 4];
            __half2 h01 = *(__half2*)&raw.x;
            __half2 h23 = *(__half2*)&raw.y;
            float2 f01 = __half22float2(h01);
            float2 f23 = __half22float2(h23);
            acc.x += a * f01.x; acc.y += a * f01.y;
            acc.z += a * f23.x; acc.w += a * f23.y;
        }
    } else {
        float mymax = -1e30f, edsum = 0.f;
        for (int base = beg; base < end; base += 64) {
            int k = base + lane;
            if (k < end) {
                int2 c2 = csr[k];
                __half2 dd = *(__half2*)&c2.y;
                float ed = __half2float(dd.y);
                edsum += ed;
                float l = hs[c2.x] + hdv + ed;
                l = (l >= 0.f) ? l : 0.2f * l;
                mymax = fmaxf(mymax, l);
            }
        }
        for (int off = 32; off; off >>= 1) {
            mymax = fmaxf(mymax, __shfl_xor(mymax, off));
            edsum += __shfl_xor(edsum, off);
        }
        lself = hsw + hdv + edsum / fmaxf((float)len, 1.0f);
        lself = (lself >= 0.f) ? lself : 0.2f * lself;
        m = fmaxf(mymax, lself);
        float psum = 0.f;
        for (int base = beg; base < end; base += 64) {
            int k = base + lane;
            if (k < end) {
                int2 c2 = csr[k];
                __half2 dd = *(__half2*)&c2.y;
                float l = hs[c2.x] + hdv + __half2float(dd.y);
                l = (l >= 0.f) ? l : 0.2f * l;
                psum += __expf(l - m);
            }
        }
        for (int off = 32; off; off >>= 1) psum += __shfl_xor(psum, off);
        psum += __expf(lself - m);
        scale = 1.f / (psum + 1e-16f);
        for (int base = beg; base < end; base += 64) {
            int k = base + lane;
            float pn = 0.f; int src = 0;
            if (k < end) {
                int2 c2 = csr[k];
                __half2 dd = *(__half2*)&c2.y;
                float l = hs[c2.x] + hdv + __half2float(dd.y);
                l = (l >= 0.f) ? l : 0.2f * l;
                pn = __expf(l - m) * scale;
                src = c2.x;
            }
            int cl = min(end - base, 64);
            for (int j = half; j < cl; j += 2) {
                float a = __shfl(pn, j);
                int sj = __shfl(src, j);
                float2 raw = *(const float2*)&feat[(size_t)sj * H_DIM + col * 4];
                __half2 h01 = *(__half2*)&raw.x;
                __half2 h23 = *(__half2*)&raw.y;
                float2 f01 = __half22float2(h01);
                float2 f23 = __half22float2(h23);
                acc.x += a * f01.x; acc.y += a * f01.y;
                acc.z += a * f23.x; acc.w += a * f23.y;
            }
        }
    }
    if (half == 0) {  // self-loop
        float a = __expf(lself - m) * scale;
        float2 raw = *(const float2*)&feat[(size_t)w * H_DIM + col * 4];
        __half2 h01 = *(__half2*)&raw.x;
        __half2 h23 = *(__half2*)&raw.y;
        float2 f01 = __half22float2(h01);
        float2 f23 = __half22float2(h23);
        acc.x += a * f01.x; acc.y += a * f01.y;
        acc.z += a * f23.x; acc.w += a * f23.y;
    }
    float4 oth;
    oth.x = __shfl(acc.x, col + 32);
    oth.y = __shfl(acc.y, col + 32);
    oth.z = __shfl(acc.z, col + 32);
    oth.w = __shfl(acc.w, col + 32);
    if (half == 0) {
        float4 o;
        o.x = acc.x + oth.x; o.y = acc.y + oth.y;
        o.z = acc.z + oth.z; o.w = acc.w + oth.w;
        __half2 q0 = __floats2half2_rn(o.x, o.y);
        __half2 q1 = __floats2half2_rn(o.z, o.w);
        int2 st; st.x = *(int*)&q0; st.y = *(int*)&q1;
        *(int2*)&t_out[(size_t)w * H_DIM + col * 4] = st;
    }
}

// ---------------------------------------------------------------------------
// K8: out = relu(T @ W + b); T is fp16.
// DO_HSHD: epilogue hs/hd for the NEXT layer.
// DO_POOL: skip the global store entirely; instead accumulate per-block fp32
//          column sums in LDS and atomicAdd 128 floats to pooled.
template <int FIN, bool DO_HSHD, bool OUT_HALF, bool DO_POOL>
__global__ __launch_bounds__(256) void gemm_kernel(const __half* __restrict__ X,
                                                   const float* __restrict__ W,
                                                   const float* __restrict__ bias,
                                                   const float* __restrict__ vs,
                                                   const float* __restrict__ vd,
                                                   void* __restrict__ HoutV,
                                                   float* __restrict__ hs,
                                                   float* __restrict__ hd,
                                                   float* __restrict__ pooled, int n) {
    __shared__ float xs[32 * FIN];
    __shared__ float psum[DO_POOL ? 128 : 1];
    int tid = threadIdx.x;
    int r0 = blockIdx.x * 32;
    if (DO_POOL && tid < 128) psum[tid] = 0.f;
    constexpr int NV = 32 * FIN / 8;  // 8 halfs (16B) per staging load
    for (int idx = tid; idx < NV; idx += 256) {
        int r = (idx * 8) / FIN, k = idx * 8 - r * FIN;
        int row = r0 + r;
        float* p = &xs[r * FIN + k];
        if (row < n) {
            int4 raw = *(const int4*)&X[(size_t)row * FIN + k];
            __half2 h0 = *(__half2*)&raw.x;
            __half2 h1 = *(__half2*)&raw.y;
            __half2 h2 = *(__half2*)&raw.z;
            __half2 h3 = *(__half2*)&raw.w;
            float2 f0 = __half22float2(h0), f1 = __half22float2(h1);
            float2 f2 = __half22float2(h2), f3 = __half22float2(h3);
            p[0] = f0.x; p[1] = f0.y; p[2] = f1.x; p[3] = f1.y;
            p[4] = f2.x; p[5] = f2.y; p[6] = f3.x; p[7] = f3.y;
        } else {
#pragma unroll
            for (int q = 0; q < 8; ++q) p[q] = 0.f;
        }
    }
    __syncthreads();
    int tcol = tid & 31;   // cols 4*tcol .. +3
    int trow = tid >> 5;   // rows 4*trow .. +3
    float acc[4][4] = {{0.f}};
    const float* wp = W + tcol * 4;
    const float* x0p = &xs[(trow * 4 + 0) * FIN];
    const float* x1p = &xs[(trow * 4 + 1) * FIN];
    const float* x2p = &xs[(trow * 4 + 2) * FIN];
    const float* x3p = &xs[(trow * 4 + 3) * FIN];
#pragma unroll 8
    for (int k = 0; k < FIN; ++k) {
        float4 w4 = *(const float4*)(wp + k * H_DIM);
        float x0 = x0p[k], x1 = x1p[k], x2 = x2p[k], x3 = x3p[k];
        acc[0][0] += x0 * w4.x; acc[0][1] += x0 * w4.y; acc[0][2] += x0 * w4.z; acc[0][3] += x0 * w4.w;
        acc[1][0] += x1 * w4.x; acc[1][1] += x1 * w4.y; acc[1][2] += x1 * w4.z; acc[1][3] += x1 * w4.w;
        acc[2][0] += x2 * w4.x; acc[2][1] += x2 * w4.y; acc[2][2] += x2 * w4.z; acc[2][3] += x2 * w4.w;
        acc[3][0] += x3 * w4.x; acc[3][1] += x3 * w4.y; acc[3][2] += x3 * w4.z; acc[3][3] += x3 * w4.w;
    }
    float4 b4 = *(const float4*)&bias[tcol * 4];
    float4 vs4, vd4;
    if (DO_HSHD) {
        vs4 = *(const float4*)&vs[tcol * 4];
        vd4 = *(const float4*)&vd[tcol * 4];
    }
    float cps0 = 0.f, cps1 = 0.f, cps2 = 0.f, cps3 = 0.f;
#pragma unroll
    for (int r = 0; r < 4; ++r) {
        int row = r0 + trow * 4 + r;
        float4 o;
        o.x = fmaxf(acc[r][0] + b4.x, 0.f);
        o.y = fmaxf(acc[r][1] + b4.y, 0.f);
        o.z = fmaxf(acc[r][2] + b4.z, 0.f);
        o.w = fmaxf(acc[r][3] + b4.w, 0.f);
        if (row < n) {
            if (DO_POOL) {
                cps0 += o.x; cps1 += o.y; cps2 += o.z; cps3 += o.w;
            } else if (OUT_HALF) {
                __half2 q0 = __floats2half2_rn(o.x, o.y);
                __half2 q1 = __floats2half2_rn(o.z, o.w);
                int2 st; st.x = *(int*)&q0; st.y = *(int*)&q1;
                *(int2*)((__half*)HoutV + (size_t)row * H_DIM + tcol * 4) = st;
            } else {
                *(float4*)((float*)HoutV + (size_t)row * H_DIM + tcol * 4) = o;
            }
        }
        if (DO_HSHD) {
            float ss = o.x * vs4.x + o.y * vs4.y + o.z * vs4.z + o.w * vs4.w;
            float sd = o.x * vd4.x + o.y * vd4.y + o.z * vd4.z + o.w * vd4.w;
            for (int off = 16; off; off >>= 1) {
                ss += __shfl_xor(ss, off);
                sd += __shfl_xor(sd, off);
            }
            if (tcol == 0 && row < n) { hs[row] = ss; hd[row] = sd; }
        }
    }
    if (DO_POOL) {
        atomicAdd(&psum[tcol * 4 + 0], cps0);
        atomicAdd(&psum[tcol * 4 + 1], cps1);
        atomicAdd(&psum[tcol * 4 + 2], cps2);
        atomicAdd(&psum[tcol * 4 + 3], cps3);
        __syncthreads();
        if (tid < 128) atomicAdd(&pooled[tid], psum[tid]);
    }
}

// ---------------------------------------------------------------------------
// K10: out = tanh(mean(h) @ Wfc + bfc)
__global__ void final_kernel(const float* __restrict__ pooled, const float* __restrict__ Wfc,
                             const float* __restrict__ bfc, float* __restrict__ out, int n) {
    int t = threadIdx.x;
    if (t >= 16) return;
    float inv_n = 1.0f / (float)n;
    float s = 0.f;
    for (int j = 0; j < 128; ++j) s += pooled[j] * inv_n * Wfc[j * 16 + t];
    out[t] = tanhf(s + bfc[t]);
}

// ---------------------------------------------------------------------------
extern "C" void kernel_launch(void* const* d_in, const int* in_sizes, int n_in,
                              void* d_out, int out_size, void* d_ws, size_t ws_size,
                              hipStream_t stream) {
    const float* x   = (const float*)d_in[0];
    const int*   ei  = (const int*)d_in[1];
    const float* ea  = (const float*)d_in[2];
    const float* W1  = (const float*)d_in[3];
    const float* We1 = (const float*)d_in[4];
    const float* as1 = (const float*)d_in[5];
    const float* ad1 = (const float*)d_in[6];
    const float* ae1 = (const float*)d_in[7];
    const float* b1  = (const float*)d_in[8];
    const float* W2  = (const float*)d_in[9];
    const float* We2 = (const float*)d_in[10];
    const float* as2 = (const float*)d_in[11];
    const float* ad2 = (const float*)d_in[12];
    const float* ae2 = (const float*)d_in[13];
    const float* b2  = (const float*)d_in[14];
    const float* Wfc = (const float*)d_in[15];
    const float* bfc = (const float*)d_in[16];
    float* out = (float*)d_out;

    const int n = in_sizes[0] / 64;      // 50000
    const int E = in_sizes[1] / 2;       // 1600000
    const int B = (n + BWID - 1) / BWID; // 391 buckets

    // workspace layout (float units, 256B-aligned blocks).
    // gcnt and pool are FIRST and contiguous -> one memset covers both.
    size_t o = 0;
    auto alloc = [&](size_t count) { size_t r = o; o += (count + 63) & ~(size_t)63; return r; };
    size_t o_gcnt   = alloc(BMAX);                // int   (512)
    size_t o_pool   = alloc(128);                 // float (contiguous after gcnt)
    size_t o_bstart = alloc(BMAX + 1);            // int
    size_t o_gcur   = alloc(BMAX);                // int
    size_t o_rowptr = alloc(n + 1);               // int
    size_t o_csr    = alloc(2 * (size_t)E);       // int2 per edge (12.8MB)
    size_t o_bufA   = alloc((size_t)n * H_DIM);   // binned int2 (early only)
    size_t o_xh     = alloc((size_t)n * 32);      // x in fp16  (n x 64 half)
    size_t o_t1h    = alloc((size_t)n * 32);      // t1 fp16    (n x 64 half)
    size_t o_o1h    = alloc((size_t)n * 64);      // out1 fp16  (n x 128 half)
    size_t o_t2h    = alloc((size_t)n * 64);      // t2 fp16    (n x 128 half)
    size_t o_hs     = alloc(n);
    size_t o_hd     = alloc(n);
    size_t o_c      = alloc(4);
    size_t o_vs1    = alloc(64);
    size_t o_vd1    = alloc(64);
    size_t o_vs2    = alloc(128);
    size_t o_vd2    = alloc(128);
    (void)ws_size;
    float* wsf = (float*)d_ws;
    int2* binned = (int2*)(wsf + o_bufA);
    int2* csr2   = (int2*)(wsf + o_csr);

    // single memset: gcnt (512 ints) + pool (128 floats), contiguous
    hipMemsetAsync(wsf + o_gcnt, 0, (BMAX + 128) * sizeof(int), stream);

    int ebg = (E + CHUNK - 1) / CHUNK;  // edge-chunk grid (391)
    int wgrid = (n + 3) / 4;            // 4 waves (nodes) per 256-thread block

    // fused prep | count (last block = prep)
    prep_count_kernel<<<ebg + 1, 256, 0, stream>>>(We1, ae1, We2, ae2,
        W1, as1, ad1, W2, as2, ad2,
        wsf + o_c, wsf + o_vs1, wsf + o_vd1, wsf + o_vs2, wsf + o_vd2,
        ei, (int*)(wsf + o_gcnt), E, B, ebg);
    bscan_kernel<<<1, BMAX, 0, stream>>>((int*)(wsf + o_gcnt), (int*)(wsf + o_bstart),
        (int*)(wsf + o_gcur), (int*)(wsf + o_rowptr), B, n, E);
    // fused bin | hshd64 (blocks >= ebg do hshd)
    bin_hshd_kernel<<<ebg + wgrid, 256, 0, stream>>>(ei, ea, wsf + o_c,
        (int*)(wsf + o_gcur), binned, E, B, ebg,
        x, wsf + o_vs1, wsf + o_vd1, wsf + o_hs, wsf + o_hd,
        (__half*)(wsf + o_xh), n);
    build_kernel<<<B, 256, 0, stream>>>((int*)(wsf + o_bstart), binned,
        (int*)(wsf + o_rowptr), csr2, n);

    // ---- layer 1 (aggregate xh fp16, then GEMM -> out1 fp16) ----
    agg64_kernel<<<wgrid, 256, 0, stream>>>((int*)(wsf + o_rowptr), csr2,
        wsf + o_hs, wsf + o_hd, (const __half*)(wsf + o_xh), (__half*)(wsf + o_t1h), n);
    gemm_kernel<64, true, true, false><<<(n + 31) / 32, 256, 0, stream>>>(
        (const __half*)(wsf + o_t1h), W1, b1, wsf + o_vs2, wsf + o_vd2,
        (void*)(wsf + o_o1h), wsf + o_hs, wsf + o_hd, nullptr, n);

    // ---- layer 2 (aggregate out1 fp16, then GEMM with fused mean-pool) ----
    agg128_kernel<<<wgrid, 256, 0, stream>>>((int*)(wsf + o_rowptr), csr2,
        wsf + o_hs, wsf + o_hd, (const __half*)(wsf + o_o1h), (__half*)(wsf + o_t2h), n);
    gemm_kernel<128, false, true, true><<<(n + 31) / 32, 256, 0, stream>>>(
        (const __half*)(wsf + o_t2h), W2, b2, nullptr, nullptr,
        nullptr, nullptr, nullptr, wsf + o_pool, n);

    // ---- head ----
    final_kernel<<<1, 64, 0, stream>>>(wsf + o_pool, Wfc, bfc, out, n);
}